// Round 5
// baseline (541.882 us; speedup 1.0000x reference)
//
#include <hip/hip_runtime.h>

// ---------------------------------------------------------------------------
// LayerStacks (NNUE-style) on MI355X.
//   h0 = clamp01( x @ (w0[b]+w_fact)^T + b0[b] )   // 1024 -> 32, bf16 MFMA
//   h1 = clamp01( h0 @ w1[b]^T + b1[b] )           // 32 -> 32,  fp32 VALU
//   out = h1 @ w2[b]^T + b2[b]                     // 32 -> 1,   fp32 VALU
// R4-R7 lesson: every __syncthreads-coupled K-loop lands at 145-180us with
// ALL pipes <12% -- latency-bound on the per-chunk load tail, barrier couples
// 4 waves to it, regardless of MFMA/weight volume (R7 halved both: slower).
// R8: BARRIER-FREE wave-private pipeline. Block = 1 wave = 32 rows, full K.
// Wave-private LDS double buffer (in-wave lgkmcnt ordering only, zero
// __syncthreads in the K loop). All 8 buckets MFMA'd per c-step (128 acc
// VGPRs, branch-free); per-row bucket select via static cndmask chain in the
// epilogue. 2048 independent single-wave blocks = 8 waves/CU, continuously
// streaming -> mimics the 6.3 TB/s copy ubench structure.
// ---------------------------------------------------------------------------

#define B_ROWS 65536
#define LK     1024       // 2*L1
#define ROWS   32         // rows per wave/block
#define NBLK   (B_ROWS / ROWS)   // 2048, exact
#define NCH    16         // K chunks of 64 elems
#define SROW   136        // LDS bytes/row/chunk (128 data + 8 pad)
#define WBUF   (ROWS * SROW)     // 4352 per buffer

// ws layout (bytes):
//   [0, 524288)       : wB bf16 B-frags of (w0+w_fact): per bucket 4096 uint4;
//                       frag c*64+l = W[bkt*32 + (l&31)][16c + 8*(l>>5) .. +8]
//   [524288, 589824)  : bktg[65536] uchar per-row bucket
#define BKT_OFF 524288

typedef short  short8  __attribute__((ext_vector_type(8)));
typedef float  f32x16  __attribute__((ext_vector_type(16)));

__device__ __forceinline__ unsigned pkbf(float a, float b) {
    // round-to-nearest-even fp32 -> bf16, packed pair (bit-trick)
    unsigned ua = __float_as_uint(a), ub = __float_as_uint(b);
    ua = (ua + 0x7FFFu + ((ua >> 16) & 1u)) >> 16;
    ub = (ub + 0x7FFFu + ((ub >> 16) & 1u)) >> 16;
    return (ua & 0xFFFFu) | (ub << 16);
}

__device__ __forceinline__ unsigned cvtpk(float a, float b) {
    // RTNE fp32->bf16 packed pair, single instruction on gfx950
    unsigned r;
    asm("v_cvt_pk_bf16_f32 %0, %1, %2" : "=v"(r) : "v"(a), "v"(b));
    return r;
}

// ls_indices may be int32 or int64. If int64, the high words (odd int32
// slots) of the first 64 elements are all zero (values 0..7). Deterministic.
__device__ __forceinline__ bool detect_i64(const int* p) {
    int acc = 0;
#pragma unroll
    for (int i = 0; i < 64; ++i) acc |= p[2 * i + 1];
    return acc == 0;
}

__device__ __forceinline__ int load_bucket(const int* p, int r, bool i64) {
    return (i64 ? p[2 * r] : p[r]) & 7;
}

// --- K1: weight prep + bucket decode ----------------------------------------
// Blocks 0..31: build bf16 B-fragments of (w0+w_fact), 1 frag/thread.
// Block 32: decode ls_indices -> bktg[65536] uchar.
__global__ __launch_bounds__(1024) void k_prep(
    const int* __restrict__ idx, const float* __restrict__ w0,
    const float* __restrict__ wf, uint4* __restrict__ wB,
    unsigned char* __restrict__ bktg)
{
    int t = threadIdx.x;
    if (blockIdx.x == 32) {
        __shared__ int s_i64;
        if (t == 0) s_i64 = detect_i64(idx) ? 1 : 0;
        __syncthreads();
        bool i64 = (s_i64 != 0);
#pragma unroll 4
        for (int j = 0; j < 64; ++j)
            bktg[j * 1024 + t] = (unsigned char)load_bucket(idx, j * 1024 + t, i64);
        return;
    }
    int f = blockIdx.x * 1024 + t;             // 32768 frags
    int b   = f >> 12;
    int i12 = f & 4095;
    int kc  = i12 >> 8;
    int i8  = i12 & 255;
    int n   = i8 & 31;
    int khi = i8 >> 5;
    int k = kc * 64 + khi * 8;                 // == c*16 + 8*(lane>>5)
    const float* p0 = w0 + (size_t)(b * 32 + n) * LK + k;
    const float* pf = wf + (size_t)n * LK + k;
    float v[8];
#pragma unroll
    for (int j = 0; j < 8; ++j) v[j] = p0[j] + pf[j];
    uint4 o;
    o.x = pkbf(v[0], v[1]); o.y = pkbf(v[2], v[3]);
    o.z = pkbf(v[4], v[5]); o.w = pkbf(v[6], v[7]);
    wB[f] = o;
}

// --- K2: main fused kernel ---------------------------------------------------
// Block = 64 thr = 1 wave, 32 consecutive rows, whole K. Per chunk (64 elems):
// issue next chunk's 8 coalesced float4 loads, MFMA current chunk (4 c-steps
// x 8 buckets), pack+ds_write next chunk. No __syncthreads in the loop;
// in-wave lgkmcnt ordering suffices (wave-private LDS). Epilogue: bucket
// select (static cndmask chain), h0 -> LDS, layers 1+2 fp32 (2 lanes/row).
__global__ __launch_bounds__(64, 2) void k_main(
    const float* __restrict__ x, const unsigned char* __restrict__ bktg,
    const uint4* __restrict__ wB, const float* __restrict__ b0,
    const float* __restrict__ w1, const float* __restrict__ b1,
    const float* __restrict__ w2, const float* __restrict__ b2,
    float* __restrict__ out)
{
    __shared__ __align__(16) unsigned char a_s[2 * WBUF];   // 8704 B
    __shared__ float hb[ROWS * 36];                         // 4608 B
    __shared__ int   bkt_w[ROWS];

    int row0 = blockIdx.x * ROWS;
    int l    = threadIdx.x;        // 0..63
    int hi   = l >> 5;
    int nn   = l & 31;

    if (l < ROWS) bkt_w[l] = (int)bktg[row0 + l];

    // staging geometry: chunk = 32 rows x 16 float4. flat idx f = q*64 + l:
    // row = 4q + (l>>4), col4 = l&15. Wave instr = 1 KB contiguous x 4 rows.
    const float4* gp = (const float4*)x + (size_t)(row0 + (l >> 4)) * 256 + (l & 15);
    const int wb_off = (l >> 4) * SROW + (l & 15) * 8;

    // ---- prologue: stage chunk 0 into buf0
    float4 v[8];
#pragma unroll
    for (int q = 0; q < 8; ++q) v[q] = gp[q * 1024];
#pragma unroll
    for (int q = 0; q < 8; ++q) {
        uint2 o; o.x = cvtpk(v[q].x, v[q].y); o.y = cvtpk(v[q].z, v[q].w);
        *(uint2*)(a_s + wb_off + q * (4 * SROW)) = o;
    }

    f32x16 acc[8];
#pragma unroll
    for (int b = 0; b < 8; ++b)
#pragma unroll
        for (int i = 0; i < 16; ++i) acc[b][i] = 0.0f;

    union UAB { uint4 u; short8 s8; };
    const int aoff = (l & 31) * SROW + 16 * hi;

    // ---- K loop: 16 chunks, wave-private double buffer, NO barriers
    for (int ck = 0; ck < NCH; ++ck) {
        const unsigned char* cur = a_s + (ck & 1) * WBUF;
        unsigned char* nxt = a_s + ((ck + 1) & 1) * WBUF;
        if (ck + 1 < NCH) {
#pragma unroll
            for (int q = 0; q < 8; ++q) v[q] = gp[q * 1024 + (ck + 1) * 16];
        }
#pragma unroll
        for (int cl = 0; cl < 4; ++cl) {
            int c = 4 * ck + cl;
            UAB ua;
            ua.u = *(const uint4*)(cur + aoff + 32 * cl);
#pragma unroll
            for (int b = 0; b < 8; ++b) {
                UAB ub;
                ub.u = wB[(size_t)b * 4096 + c * 64 + l];   // L2-resident
                acc[b] = __builtin_amdgcn_mfma_f32_32x32x16_bf16(
                             ua.s8, ub.s8, acc[b], 0, 0, 0);
            }
        }
        if (ck + 1 < NCH) {
#pragma unroll
            for (int q = 0; q < 8; ++q) {
                uint2 o; o.x = cvtpk(v[q].x, v[q].y); o.y = cvtpk(v[q].z, v[q].w);
                *(uint2*)(nxt + wb_off + q * (4 * SROW)) = o;
            }
        }
    }

    // ---- per-row bucket select (all static indexing; mb only in compares)
    float b0v[8];
#pragma unroll
    for (int b = 0; b < 8; ++b) b0v[b] = b0[b * 32 + nn];
#pragma unroll
    for (int i = 0; i < 16; ++i) {
        int m  = (i & 3) + 8 * (i >> 2) + 4 * hi;   // row in tile
        int mb = bkt_w[m];
        float s  = acc[0][i];
        float bv = b0v[0];
#pragma unroll
        for (int b = 1; b < 8; ++b) {
            bool e = (mb == b);
            s  = e ? acc[b][i] : s;
            bv = e ? b0v[b] : bv;
        }
        float h = s + bv;
        hb[m * 36 + nn] = fminf(fmaxf(h, 0.0f), 1.0f);
    }
    // wave-internal ds ordering; compiler inserts lgkmcnt before reads below

    // ---- layers 1+2 (fp32): 2 lanes/row, 16 outputs each
    {
        int r = l >> 1, half = l & 1;
        int bkt = bkt_w[r];
        const float4* hr = (const float4*)(hb + r * 36);
        float4 ha[8];
#pragma unroll
        for (int q = 0; q < 8; ++q) ha[q] = hr[q];
        const float* w1b = w1 + (size_t)bkt * 1024;
        const float* b1b = b1 + bkt * 32;
        const float* w2b = w2 + bkt * 32;
        float partial = 0.0f;
#pragma unroll
        for (int jj = 0; jj < 16; ++jj) {
            int j2 = half * 16 + jj;
            const float4* wr = (const float4*)&w1b[j2 * 32];
            float s = b1b[j2];
#pragma unroll
            for (int q = 0; q < 8; ++q) {
                float4 w4 = wr[q];
                s += ha[q].x * w4.x + ha[q].y * w4.y + ha[q].z * w4.z + ha[q].w * w4.w;
            }
            s = fminf(fmaxf(s, 0.0f), 1.0f);
            partial += s * w2b[j2];
        }
        partial += __shfl_xor(partial, 1);
        if (half == 0) out[row0 + r] = partial + b2[bkt];
    }
}

// ---------------------------------------------------------------------------
extern "C" void kernel_launch(void* const* d_in, const int* in_sizes, int n_in,
                              void* d_out, int out_size, void* d_ws, size_t ws_size,
                              hipStream_t stream) {
    const float* x   = (const float*)d_in[0];
    const int*   lsi = (const int*)  d_in[1];
    const float* wf  = (const float*)d_in[2];
    const float* w0  = (const float*)d_in[3];
    const float* b0  = (const float*)d_in[4];
    const float* w1  = (const float*)d_in[5];
    const float* b1  = (const float*)d_in[6];
    const float* w2  = (const float*)d_in[7];
    const float* b2  = (const float*)d_in[8];
    float* out = (float*)d_out;

    char* ws = (char*)d_ws;
    uint4* wB = (uint4*)ws;
    unsigned char* bktg = (unsigned char*)(ws + BKT_OFF);

    k_prep<<<33, 1024, 0, stream>>>(lsi, w0, wf, wB, bktg);
    k_main<<<NBLK, 64, 0, stream>>>(x, bktg, wB, b0, w1, b1, w2, b2, out);
}

// Round 6
// 417.756 us; speedup vs baseline: 1.2971x; 1.2971x over previous
//
#include <hip/hip_runtime.h>

// ---------------------------------------------------------------------------
// LayerStacks (NNUE-style) on MI355X.
//   h0 = clamp01( x @ (w0[b]+w_fact)^T + b0[b] )   // 1024 -> 32, bf16 MFMA
//   h1 = clamp01( h0 @ w1[b]^T + b1[b] )           // 32 -> 32,  fp32 VALU
//   out = h1 @ w2[b]^T + b2[b]                     // 32 -> 1,   fp32 VALU
// R4-R8 model: dur = FETCH/BW with BW 0.5-0.9 TB/s; Little's law => ~1 KB
// outstanding per CU => waves hold loads in flight ~5% of the time. Cause:
// ONE vmcnt counter per wave + weight loads interleaved per-MFMA => serial
// ~200cyc L2 ladder per chunk, and x-prefetch (older in queue) force-drained
// by the first weight wait. R8 (barrier-free) made it worse, not better.
// R9: within R6's shape, (1) BATCH the chunk's 16 weight loads into regs at
// chunk start (one wait, MFMAs run from registers), (2) issue x-prefetch
// AFTER the weight batch (newest in queue -> survives the whole chunk in
// flight), (3) KC=128, small LDS, launch_bounds(256,3): 12 waves/CU x 4KB
// in flight ~ 48KB/CU outstanding >> 9.2KB needed for fair-share HBM.
// ---------------------------------------------------------------------------

#define B_ROWS 65536
#define LK     1024       // 2*L1
#define TILE   32
#define NBLK   (B_ROWS / TILE)   // 2048, exact
#define KC     128        // K-chunk in fp32 elems
#define NCH    (LK / KC)  // 8
#define SROW   264        // LDS bytes/row/chunk (256 bf16 data + 8 pad)
#define BUFSZ  (TILE * SROW)     // 8448

// ws layout (bytes):
//   [0, 524288)       : wB bf16 B-frags of (w0+w_fact): per bucket 4096 uint4;
//                       frag c*64+l = W[bkt*32 + (l&31)][16c + 8*(l>>5) .. +8]
//   [524288, 589824)  : bktg[65536] uchar per-row bucket
#define BKT_OFF 524288

typedef short  short8  __attribute__((ext_vector_type(8)));
typedef float  f32x16  __attribute__((ext_vector_type(16)));

__device__ __forceinline__ unsigned pkbf(float a, float b) {
    // round-to-nearest-even fp32 -> bf16, packed pair (bit-trick)
    unsigned ua = __float_as_uint(a), ub = __float_as_uint(b);
    ua = (ua + 0x7FFFu + ((ua >> 16) & 1u)) >> 16;
    ub = (ub + 0x7FFFu + ((ub >> 16) & 1u)) >> 16;
    return (ua & 0xFFFFu) | (ub << 16);
}

__device__ __forceinline__ unsigned cvtpk(float a, float b) {
    // RTNE fp32->bf16 packed pair, single instruction on gfx950
    unsigned r;
    asm("v_cvt_pk_bf16_f32 %0, %1, %2" : "=v"(r) : "v"(a), "v"(b));
    return r;
}

// ls_indices may be int32 or int64. If int64, the high words (odd int32
// slots) of the first 64 elements are all zero (values 0..7). Deterministic.
__device__ __forceinline__ bool detect_i64(const int* p) {
    int acc = 0;
#pragma unroll
    for (int i = 0; i < 64; ++i) acc |= p[2 * i + 1];
    return acc == 0;
}

__device__ __forceinline__ int load_bucket(const int* p, int r, bool i64) {
    return (i64 ? p[2 * r] : p[r]) & 7;
}

// --- K1: weight prep + bucket decode ----------------------------------------
// Blocks 0..31: build bf16 B-fragments of (w0+w_fact), 1 frag/thread.
// Block 32: decode ls_indices -> bktg[65536] uchar.
__global__ __launch_bounds__(1024) void k_prep(
    const int* __restrict__ idx, const float* __restrict__ w0,
    const float* __restrict__ wf, uint4* __restrict__ wB,
    unsigned char* __restrict__ bktg)
{
    int t = threadIdx.x;
    if (blockIdx.x == 32) {
        __shared__ int s_i64;
        if (t == 0) s_i64 = detect_i64(idx) ? 1 : 0;
        __syncthreads();
        bool i64 = (s_i64 != 0);
#pragma unroll 4
        for (int j = 0; j < 64; ++j)
            bktg[j * 1024 + t] = (unsigned char)load_bucket(idx, j * 1024 + t, i64);
        return;
    }
    int f = blockIdx.x * 1024 + t;             // 32768 frags
    int b   = f >> 12;
    int i12 = f & 4095;
    int kc  = i12 >> 8;
    int i8  = i12 & 255;
    int n   = i8 & 31;
    int khi = i8 >> 5;
    int k = kc * 64 + khi * 8;                 // == c*16 + 8*(lane>>5)
    const float* p0 = w0 + (size_t)(b * 32 + n) * LK + k;
    const float* pf = wf + (size_t)n * LK + k;
    float v[8];
#pragma unroll
    for (int j = 0; j < 8; ++j) v[j] = p0[j] + pf[j];
    uint4 o;
    o.x = pkbf(v[0], v[1]); o.y = pkbf(v[2], v[3]);
    o.z = pkbf(v[4], v[5]); o.w = pkbf(v[6], v[7]);
    wB[f] = o;
}

// --- K2: main fused kernel ---------------------------------------------------
// Block = 256 thr = 4 waves; 32 consecutive rows; K in 8 chunks of 128,
// LDS double-buffered. Per chunk: [batch 16 weight uint4 -> regs] ->
// [issue 4 x-float4 prefetch (next chunk)] -> [8x2 MFMA from regs+LDS] ->
// [pack+ds_write next chunk] -> barrier. Wave wv owns buckets {2wv, 2wv+1};
// epilogue selects per-row bucket, layers 1+2 fp32 (weights L2-resident).
__global__ __launch_bounds__(256, 3) void k_main(
    const float* __restrict__ x, const unsigned char* __restrict__ bktg,
    const uint4* __restrict__ wB, const float* __restrict__ b0,
    const float* __restrict__ w1, const float* __restrict__ b1,
    const float* __restrict__ w2, const float* __restrict__ b2,
    float* __restrict__ out)
{
    __shared__ __align__(16) unsigned char a_s[2 * BUFSZ];  // 16896 B
    __shared__ float hb[TILE * 36];                         // 4608 B
    __shared__ int   bkt_s[TILE];

    int row0 = blockIdx.x * TILE;
    int t    = threadIdx.x;
    int lane = t & 63;
    int wv   = t >> 6;
    int hi   = lane >> 5;
    int nn   = lane & 31;

    if (t < TILE) bkt_s[t] = (int)bktg[row0 + t];

    // staging geometry: chunk = 32 rows x 32 float4 (512 B fp32 per row).
    // flat f = 256q + t: row = 8q + (t>>5), col4 = t&31. Per wave-instr:
    // 2 rows x 512 B contiguous. ck advances 32 float4 within the row.
    const float4* gp = (const float4*)x + (size_t)(row0 + (t >> 5)) * 256 + (t & 31);
    const int wb_off = (t >> 5) * SROW + (t & 31) * 8;   // uint2 (8 B) per float4

    // ---- prologue: stage chunk 0 into buf0
    float4 v[4];
#pragma unroll
    for (int q = 0; q < 4; ++q) v[q] = gp[q * 2048];
#pragma unroll
    for (int q = 0; q < 4; ++q) {
        uint2 o; o.x = cvtpk(v[q].x, v[q].y); o.y = cvtpk(v[q].z, v[q].w);
        *(uint2*)(a_s + wb_off + q * 8 * SROW) = o;
    }
    __syncthreads();

    const uint4* wB0 = wB + (size_t)(2 * wv) * 4096 + lane;
    const uint4* wB1 = wB0 + 4096;

    f32x16 acc0, acc1;
#pragma unroll
    for (int i = 0; i < 16; ++i) { acc0[i] = 0.0f; acc1[i] = 0.0f; }

    union UAB { uint4 u; short8 s8; };

    for (int ck = 0; ck < NCH; ++ck) {
        const unsigned char* cur = a_s + (ck & 1) * BUFSZ;
        unsigned char* nxt = a_s + ((ck + 1) & 1) * BUFSZ;

        // 1. batched weight loads for this chunk (one wait, no per-MFMA ladder)
        UAB w0r[8], w1r[8];
#pragma unroll
        for (int cc = 0; cc < 8; ++cc) w0r[cc].u = wB0[(ck * 8 + cc) * 64];
#pragma unroll
        for (int cc = 0; cc < 8; ++cc) w1r[cc].u = wB1[(ck * 8 + cc) * 64];

        // 2. x prefetch for next chunk -- newest in vmcnt queue, stays in
        //    flight across the whole MFMA phase.
        if (ck + 1 < NCH) {
#pragma unroll
            for (int q = 0; q < 4; ++q) v[q] = gp[q * 2048 + (ck + 1) * 32];
        }

        // 3. MFMA from LDS A + register B
        const unsigned char* Ab = cur + (size_t)(lane & 31) * SROW + 16 * hi;
#pragma unroll
        for (int cc = 0; cc < 8; ++cc) {
            UAB ua;
            ua.u = *(const uint4*)(Ab + 32 * cc);         // 2-way alias = free
            acc0 = __builtin_amdgcn_mfma_f32_32x32x16_bf16(ua.s8, w0r[cc].s8, acc0, 0, 0, 0);
            acc1 = __builtin_amdgcn_mfma_f32_32x32x16_bf16(ua.s8, w1r[cc].s8, acc1, 0, 0, 0);
        }

        // 4. pack + write next chunk
        if (ck + 1 < NCH) {
#pragma unroll
            for (int q = 0; q < 4; ++q) {
                uint2 o; o.x = cvtpk(v[q].x, v[q].y); o.y = cvtpk(v[q].z, v[q].w);
                *(uint2*)(nxt + wb_off + q * 8 * SROW) = o;
            }
        }
        __syncthreads();
    }

    // ---- select per-row bucket: C elem (reg i, lane l):
    //      m = (i&3)+8*(i>>2)+4*(l>>5), n = l&31
    int bb0 = 2 * wv, bb1 = 2 * wv + 1;
#pragma unroll
    for (int i = 0; i < 16; ++i) {
        int m = (i & 3) + 8 * (i >> 2) + 4 * hi;
        int mb = bkt_s[m];
        if (mb == bb0 || mb == bb1) {
            float s = (mb == bb0) ? acc0[i] : acc1[i];
            float h = s + b0[mb * 32 + nn];
            hb[m * 36 + nn] = fminf(fmaxf(h, 0.0f), 1.0f);
        }
    }
    __syncthreads();

    // ---- layers 1+2 (fp32), threads 0..63: pair (2r,2r+1) splits 32 outputs
    if (t < 64) {
        int r = t >> 1, half = t & 1;
        int bkt = bkt_s[r];
        const float4* hr = (const float4*)(hb + r * 36);
        float4 ha[8];
#pragma unroll
        for (int q = 0; q < 8; ++q) ha[q] = hr[q];
        const float* w1b = w1 + (size_t)bkt * 1024;
        const float* b1b = b1 + bkt * 32;
        const float* w2b = w2 + bkt * 32;
        float partial = 0.0f;
#pragma unroll
        for (int jj = 0; jj < 16; ++jj) {
            int j2 = half * 16 + jj;
            const float4* wr = (const float4*)&w1b[j2 * 32];
            float s = b1b[j2];
#pragma unroll
            for (int q = 0; q < 8; ++q) {
                float4 w4 = wr[q];
                s += ha[q].x * w4.x + ha[q].y * w4.y + ha[q].z * w4.z + ha[q].w * w4.w;
            }
            s = fminf(fmaxf(s, 0.0f), 1.0f);
            partial += s * w2b[j2];
        }
        partial += __shfl_xor(partial, 1);
        if (half == 0) out[row0 + r] = partial + b2[bkt];
    }
}

// ---------------------------------------------------------------------------
extern "C" void kernel_launch(void* const* d_in, const int* in_sizes, int n_in,
                              void* d_out, int out_size, void* d_ws, size_t ws_size,
                              hipStream_t stream) {
    const float* x   = (const float*)d_in[0];
    const int*   lsi = (const int*)  d_in[1];
    const float* wf  = (const float*)d_in[2];
    const float* w0  = (const float*)d_in[3];
    const float* b0  = (const float*)d_in[4];
    const float* w1  = (const float*)d_in[5];
    const float* b1  = (const float*)d_in[6];
    const float* w2  = (const float*)d_in[7];
    const float* b2  = (const float*)d_in[8];
    float* out = (float*)d_out;

    char* ws = (char*)d_ws;
    uint4* wB = (uint4*)ws;
    unsigned char* bktg = (unsigned char*)(ws + BKT_OFF);

    k_prep<<<33, 1024, 0, stream>>>(lsi, w0, wf, wB, bktg);
    k_main<<<NBLK, 256, 0, stream>>>(x, bktg, wB, b0, w1, b1, w2, b2, out);
}